// Round 11
// baseline (124.453 us; speedup 1.0000x reference)
//
#include <hip/hip_runtime.h>
#include <stdint.h>
#include <stddef.h>

#define NB 4
#define NL 2048
#define MODEL 512
#define NH 8
#define HD 64

// Q pre-scale: (1/sqrt(64)) * log2(e) -> scores in log2 domain
#define QSCALE 0.18033688011112042f

typedef __attribute__((ext_vector_type(8))) short short8;
typedef __attribute__((ext_vector_type(8))) __bf16 bf16x8;
typedef __attribute__((ext_vector_type(4))) float f32x4;
typedef __attribute__((ext_vector_type(16))) float f32x16;
typedef __attribute__((ext_vector_type(2))) unsigned int u32x2;

// round-to-nearest-even fp32 -> bf16 (bit pattern)
static __device__ __forceinline__ unsigned short f2bf(float x) {
  union { float f; unsigned u; } v; v.f = x;
  unsigned r = v.u + 0x7FFFu + ((v.u >> 16) & 1u);
  return (unsigned short)(r >> 16);
}

// packed fp32x2 -> bf16x2 (single HW instruction)
static __device__ __forceinline__ unsigned cvtpk(float lo, float hi) {
  unsigned r;
  asm("v_cvt_pk_bf16_f32 %0, %1, %2" : "=v"(r) : "v"(lo), "v"(hi));
  return r;
}

static __device__ __forceinline__ f32x4 mfma16(short8 a, short8 b, f32x4 c) {
  return __builtin_amdgcn_mfma_f32_16x16x32_bf16(
      __builtin_bit_cast(bf16x8, a), __builtin_bit_cast(bf16x8, b), c, 0, 0, 0);
}

static __device__ __forceinline__ f32x16 mfma32(short8 a, short8 b, f32x16 c) {
  return __builtin_amdgcn_mfma_f32_32x32x16_bf16(
      __builtin_bit_cast(bf16x8, a), __builtin_bit_cast(bf16x8, b), c, 0, 0, 0);
}

#define GLOAD_LDS(gp, lp)                                                      \
  __builtin_amdgcn_global_load_lds(                                            \
      (const __attribute__((address_space(1))) void*)(gp),                     \
      (__attribute__((address_space(3))) void*)(lp), 16, 0, 0)

// ---------------------------------------------------------------------------
// Weight pre-convert: Wq (scaled by QSCALE), Wk, Wv, Wo fp32 -> bf16.
// 4 x 262144 elements; grid 256 x 256, 16 elems/thread.
// ---------------------------------------------------------------------------
__global__ __launch_bounds__(256) void cvtW(const float* __restrict__ Wq,
                                            const float* __restrict__ Wk,
                                            const float* __restrict__ Wv,
                                            const float* __restrict__ Wo,
                                            unsigned short* __restrict__ out) {
  const size_t e = ((size_t)blockIdx.x * 256 + threadIdx.x) * 16;
  const int which = (int)(e >> 18);               // 262144 per matrix
  const size_t off = e & 262143;
  const float* s = (which == 0 ? Wq : which == 1 ? Wk : which == 2 ? Wv : Wo) + off;
  const float sc = (which == 0) ? QSCALE : 1.0f;

  float4 a0 = *(const float4*)(s);
  float4 a1 = *(const float4*)(s + 4);
  float4 a2 = *(const float4*)(s + 8);
  float4 a3 = *(const float4*)(s + 12);
  uint4 o0, o1;
  o0.x = cvtpk(a0.x * sc, a0.y * sc); o0.y = cvtpk(a0.z * sc, a0.w * sc);
  o0.z = cvtpk(a1.x * sc, a1.y * sc); o0.w = cvtpk(a1.z * sc, a1.w * sc);
  o1.x = cvtpk(a2.x * sc, a2.y * sc); o1.y = cvtpk(a2.z * sc, a2.w * sc);
  o1.z = cvtpk(a3.x * sc, a3.y * sc); o1.w = cvtpk(a3.z * sc, a3.w * sc);
  *(uint4*)(out + e) = o0;
  *(uint4*)(out + e + 8) = o1;
}

// ---------------------------------------------------------------------------
// Merged Q/K/V projection: grid 768 = 3 x 256, 256 thr (4 waves 2x2).
// W operand is PRE-CONVERTED bf16 (QSCALE baked into Wq) -> W staging is a
// plain uint4 copy (no cvtpk). A staged with fp32->bf16 convert as before.
// which 0: Q bf16, 1: K bf16, 2: V transposed Vt[b][n][s].
// ---------------------------------------------------------------------------
__global__ __launch_bounds__(256) void qkv512(const float* __restrict__ Aq,
                                              const float* __restrict__ Ak,
                                              const float* __restrict__ Av,
                                              const unsigned short* __restrict__ Wb,
                                              unsigned short* __restrict__ Qo,
                                              unsigned short* __restrict__ Ko,
                                              unsigned short* __restrict__ Vto) {
  __shared__ unsigned short Alds[128][72];
  __shared__ unsigned short Wlds[128][72];

  const int which = blockIdx.x >> 8;
  const int bid = blockIdx.x & 255;
  const float* A = which == 0 ? Aq : which == 1 ? Ak : Av;
  const unsigned short* W = Wb + (size_t)which * 262144;

  const int tid = threadIdx.x;
  const int bn = bid & 3;
  const int bm = bid >> 2;
  const int mbase = bm * 128, nbase = bn * 128;
  const int wid = tid >> 6, lane = tid & 63;
  const int lo = lane & 15, grp = lane >> 4;
  const int wm = wid >> 1, wn = wid & 1;

  f32x4 acc[4][4] = {};

#pragma unroll 1
  for (int kb = 0; kb < 8; ++kb) {
#pragma unroll
    for (int it = 0; it < 8; ++it) {
      int id = tid + it * 256;
      int row = id >> 4, cg = id & 15;
      float4 v = *(const float4*)(A + (size_t)(mbase + row) * 512 + kb * 64 + cg * 4);
      uint2 w; w.x = cvtpk(v.x, v.y); w.y = cvtpk(v.z, v.w);
      *(uint2*)&Alds[row][cg * 4] = w;
    }
#pragma unroll
    for (int it = 0; it < 4; ++it) {
      int id = tid + it * 256;
      int row = id >> 3, cg = id & 7;
      uint4 v = *(const uint4*)(W + (size_t)(nbase + row) * 512 + kb * 64 + cg * 8);
      *(uint4*)&Wlds[row][cg * 8] = v;
    }
    __syncthreads();

#pragma unroll
    for (int kk = 0; kk < 2; ++kk) {
      short8 aw[4], ba[4];
#pragma unroll
      for (int f = 0; f < 4; ++f)
        aw[f] = *(const short8*)&Wlds[wn * 64 + f * 16 + lo][kk * 32 + grp * 8];
#pragma unroll
      for (int f = 0; f < 4; ++f)
        ba[f] = *(const short8*)&Alds[wm * 64 + f * 16 + lo][kk * 32 + grp * 8];
#pragma unroll
      for (int mf = 0; mf < 4; ++mf)
#pragma unroll
        for (int nf = 0; nf < 4; ++nf)
          acc[mf][nf] = mfma16(aw[nf], ba[mf], acc[mf][nf]);
    }
    __syncthreads();
  }

#pragma unroll
  for (int mf = 0; mf < 4; ++mf)
#pragma unroll
    for (int nf = 0; nf < 4; ++nf) {
      int m = mbase + wm * 64 + mf * 16 + lo;
      int n0 = nbase + wn * 64 + nf * 16 + grp * 4;
      f32x4 a = acc[mf][nf];
      if (which < 2) {
        unsigned short* C = which == 0 ? Qo : Ko;
        uint2 w;
        w.x = cvtpk(a[0], a[1]);
        w.y = cvtpk(a[2], a[3]);
        *(uint2*)(C + (size_t)m * 512 + n0) = w;
      } else {
        int b = m >> 11, s = m & 2047;
#pragma unroll
        for (int i = 0; i < 4; ++i)
          Vto[((size_t)b * 512 + n0 + i) * 2048 + s] = f2bf(a[i]);
      }
    }
}

// ---------------------------------------------------------------------------
// Output projection (bf16 A, bf16 pre-converted W, fp32 out). 128x128, grid 256.
// ---------------------------------------------------------------------------
__global__ __launch_bounds__(256) void gemmWo(const unsigned short* __restrict__ A,
                                              const unsigned short* __restrict__ W,
                                              float* __restrict__ C) {
  __shared__ unsigned short Alds[128][72];
  __shared__ unsigned short Wlds[128][72];

  const int tid = threadIdx.x;
  const int bn = blockIdx.x & 3;
  const int bm = blockIdx.x >> 2;
  const int mbase = bm * 128, nbase = bn * 128;
  const int wid = tid >> 6, lane = tid & 63;
  const int lo = lane & 15, grp = lane >> 4;
  const int wm = wid >> 1, wn = wid & 1;

  f32x4 acc[4][4] = {};

#pragma unroll 1
  for (int kb = 0; kb < 8; ++kb) {
#pragma unroll
    for (int it = 0; it < 4; ++it) {
      int id = tid + it * 256;
      int row = id >> 3, cg = id & 7;
      uint4 v = *(const uint4*)(A + (size_t)(mbase + row) * 512 + kb * 64 + cg * 8);
      *(uint4*)&Alds[row][cg * 8] = v;
    }
#pragma unroll
    for (int it = 0; it < 4; ++it) {
      int id = tid + it * 256;
      int row = id >> 3, cg = id & 7;
      uint4 v = *(const uint4*)(W + (size_t)(nbase + row) * 512 + kb * 64 + cg * 8);
      *(uint4*)&Wlds[row][cg * 8] = v;
    }
    __syncthreads();

#pragma unroll
    for (int kk = 0; kk < 2; ++kk) {
      short8 aw[4], ba[4];
#pragma unroll
      for (int f = 0; f < 4; ++f)
        aw[f] = *(const short8*)&Wlds[wn * 64 + f * 16 + lo][kk * 32 + grp * 8];
#pragma unroll
      for (int f = 0; f < 4; ++f)
        ba[f] = *(const short8*)&Alds[wm * 64 + f * 16 + lo][kk * 32 + grp * 8];
#pragma unroll
      for (int mf = 0; mf < 4; ++mf)
#pragma unroll
        for (int nf = 0; nf < 4; ++nf)
          acc[mf][nf] = mfma16(aw[nf], ba[mf], acc[mf][nf]);
    }
    __syncthreads();
  }

#pragma unroll
  for (int mf = 0; mf < 4; ++mf)
#pragma unroll
    for (int nf = 0; nf < 4; ++nf) {
      int m = mbase + wm * 64 + mf * 16 + lo;
      int n0 = nbase + wn * 64 + nf * 16 + grp * 4;
      f32x4 a = acc[mf][nf];
      float4 o;
      o.x = a[0]; o.y = a[1]; o.z = a[2]; o.w = a[3];
      *(float4*)(C + (size_t)m * 512 + n0) = o;
    }
}

// ---------------------------------------------------------------------------
// Flash attention (r9 version, verbatim): barrier-free main loop, wave-private
// dbuf LDS via global_load_lds + counted vmcnt, dual 32-q chains, unnormalized
// softmax (P = exp2(s)), l via ones-MFMA, in-register P via cvt_pk + permlane.
// Grid 512 x 4 waves (2 blocks/CU). XCD swizzle.
// ---------------------------------------------------------------------------
__global__ __launch_bounds__(256, 2) void attn_nb(const unsigned short* __restrict__ Qg,
                                                  const unsigned short* __restrict__ Kg,
                                                  const unsigned short* __restrict__ Vt,
                                                  unsigned short* __restrict__ Og) {
  __shared__ __align__(16) char LDS[65536];

  const int tid = threadIdx.x;
  const int wid = tid >> 6, lane = tid & 63;
  const int ln31 = lane & 31, hl = lane >> 5;
  const int qh = wid & 1, sh = wid >> 1;

  // XCD chunk swizzle (512 blocks, 64/XCD = 4 bh groups)
  const int lb = ((blockIdx.x & 7) << 6) | (blockIdx.x >> 3);
  const int bh = lb >> 4, qb = lb & 15;
  const int b = bh >> 3, h = bh & 7;

  const unsigned short* Kbh = Kg + (size_t)b * 2048 * 512 + h * 64;
  const unsigned short* Vbh = Vt + ((size_t)b * 512 + h * 64) * 2048;
  const int q0 = qb * 128 + qh * 64 + ln31;   // chain A; chain B = q0+32

  // Q B-fragments
  short8 qfA[4], qfB[4];
#pragma unroll
  for (int ks = 0; ks < 4; ++ks) {
    qfA[ks] = *(const short8*)(Qg + ((size_t)b * 2048 + q0) * 512 + h * 64 + ks * 16 + hl * 8);
    qfB[ks] = *(const short8*)(Qg + ((size_t)b * 2048 + q0 + 32) * 512 + h * 64 + ks * 16 + hl * 8);
  }

  // wave-private LDS: K [2][4096] at +0, V [2][4096] at +8192
  char* kbuf = LDS + wid * 16384;
  char* vbuf = kbuf + 8192;

  // staging geometry (pre-swizzled global source; LDS dest linear lane*16)
  const int krow = lane >> 3;                       // 0..7
  const int kslot = (lane & 7) ^ krow;              // K: slot ^= row&7
  const int vrow = lane >> 2;                       // 0..15
  const int vslot = (lane & 3) ^ ((vrow >> 1) & 3); // V: slot ^= (row>>1)&3
  const int sbase = sh * 1024;
  const unsigned short* kg = Kbh + (size_t)(sbase + krow) * 512 + kslot * 8;
  const unsigned short* vg = Vbh + (size_t)vrow * 2048 + sbase + vslot * 8;

  // read addressing
  const int ksw = ln31 & 7;
  const int vsw = (ln31 >> 1) & 3;
  const int krd = ln31 * 128;

  const short8 ones = {0x3F80, 0x3F80, 0x3F80, 0x3F80, 0x3F80, 0x3F80, 0x3F80, 0x3F80};
  f32x16 oA0 = {}, oA1 = {}, oB0 = {}, oB1 = {}, lA = {}, lB = {};

#define STAGE(t, bufi)                                                         \
  {                                                                            \
    const unsigned short* kp_ = kg + (size_t)(t) * 32 * 512;                   \
    const unsigned short* vp_ = vg + (t) * 32;                                 \
    char* kd_ = kbuf + (bufi) * 4096;                                          \
    char* vd_ = vbuf + (bufi) * 4096;                                          \
    GLOAD_LDS(kp_, kd_);                                                       \
    GLOAD_LDS(kp_ + (size_t)8 * 512, kd_ + 1024);                              \
    GLOAD_LDS(kp_ + (size_t)16 * 512, kd_ + 2048);                             \
    GLOAD_LDS(kp_ + (size_t)24 * 512, kd_ + 3072);                             \
    GLOAD_LDS(vp_, vd_);                                                       \
    GLOAD_LDS(vp_ + (size_t)16 * 2048, vd_ + 1024);                            \
    GLOAD_LDS(vp_ + (size_t)32 * 2048, vd_ + 2048);                            \
    GLOAD_LDS(vp_ + (size_t)48 * 2048, vd_ + 3072);                            \
  }

#define COMPUTE(bufi)                                                          \
  {                                                                            \
    const char* kr_ = kbuf + (bufi) * 4096;                                    \
    const char* vr_ = vbuf + (bufi) * 4096;                                    \
    short8 k0 = *(const short8*)(kr_ + krd + (((0 + hl) ^ ksw) << 4));         \
    short8 k1 = *(const short8*)(kr_ + krd + (((2 + hl) ^ ksw) << 4));         \
    short8 k2 = *(const short8*)(kr_ + krd + (((4 + hl) ^ ksw) << 4));         \
    short8 k3 = *(const short8*)(kr_ + krd + (((6 + hl) ^ ksw) << 4));         \
    short8 v00 = *(const short8*)(vr_ + (0 * 32 + ln31) * 64 + (((0 + hl) ^ vsw) << 4)); \
    short8 v01 = *(const short8*)(vr_ + (1 * 32 + ln31) * 64 + (((0 + hl) ^ vsw) << 4)); \
    short8 v10 = *(const short8*)(vr_ + (0 * 32 + ln31) * 64 + (((2 + hl) ^ vsw) << 4)); \
    short8 v11 = *(const short8*)(vr_ + (1 * 32 + ln31) * 64 + (((2 + hl) ^ vsw) << 4)); \
    f32x16 sA = {}, sB = {};                                                   \
    __builtin_amdgcn_s_setprio(1);                                             \
    sA = mfma32(k0, qfA[0], sA); sA = mfma32(k1, qfA[1], sA);                  \
    sA = mfma32(k2, qfA[2], sA); sA = mfma32(k3, qfA[3], sA);                  \
    sB = mfma32(k0, qfB[0], sB); sB = mfma32(k1, qfB[1], sB);                  \
    sB = mfma32(k2, qfB[2], sB); sB = mfma32(k3, qfB[3], sB);                  \
    __builtin_amdgcn_s_setprio(0);                                             \
    unsigned cA[8], cB[8];                                                     \
    _Pragma("unroll")                                                          \
    for (int i = 0; i < 8; ++i)                                                \
      cA[i] = cvtpk(__builtin_exp2f(sA[2 * i]), __builtin_exp2f(sA[2 * i + 1]));\
    _Pragma("unroll")                                                          \
    for (int i = 0; i < 8; ++i)                                                \
      cB[i] = cvtpk(__builtin_exp2f(sB[2 * i]), __builtin_exp2f(sB[2 * i + 1]));\
    {                                                                          \
      u32x2 r;                                                                 \
      r = __builtin_amdgcn_permlane32_swap(cA[0], cA[2], false, false); cA[0] = r[0]; cA[2] = r[1]; \
      r = __builtin_amdgcn_permlane32_swap(cA[1], cA[3], false, false); cA[1] = r[0]; cA[3] = r[1]; \
      r = __builtin_amdgcn_permlane32_swap(cA[4], cA[6], false, false); cA[4] = r[0]; cA[6] = r[1]; \
      r = __builtin_amdgcn_permlane32_swap(cA[5], cA[7], false, false); cA[5] = r[0]; cA[7] = r[1]; \
      r = __builtin_amdgcn_permlane32_swap(cB[0], cB[2], false, false); cB[0] = r[0]; cB[2] = r[1]; \
      r = __builtin_amdgcn_permlane32_swap(cB[1], cB[3], false, false); cB[1] = r[0]; cB[3] = r[1]; \
      r = __builtin_amdgcn_permlane32_swap(cB[4], cB[6], false, false); cB[4] = r[0]; cB[6] = r[1]; \
      r = __builtin_amdgcn_permlane32_swap(cB[5], cB[7], false, false); cB[5] = r[0]; cB[7] = r[1]; \
    }                                                                          \
    short8 pA0, pA1, pB0, pB1;                                                 \
    {                                                                          \
      union { unsigned u[4]; short8 s8; } t2;                                  \
      t2.u[0] = cA[0]; t2.u[1] = cA[1]; t2.u[2] = cA[2]; t2.u[3] = cA[3]; pA0 = t2.s8; \
      t2.u[0] = cA[4]; t2.u[1] = cA[5]; t2.u[2] = cA[6]; t2.u[3] = cA[7]; pA1 = t2.s8; \
      t2.u[0] = cB[0]; t2.u[1] = cB[1]; t2.u[2] = cB[2]; t2.u[3] = cB[3]; pB0 = t2.s8; \
      t2.u[0] = cB[4]; t2.u[1] = cB[5]; t2.u[2] = cB[6]; t2.u[3] = cB[7]; pB1 = t2.s8; \
    }                                                                          \
    __builtin_amdgcn_s_setprio(1);                                             \
    oA0 = mfma32(v00, pA0, oA0); oA1 = mfma32(v01, pA0, oA1);                  \
    oB0 = mfma32(v00, pB0, oB0); oB1 = mfma32(v01, pB0, oB1);                  \
    lA = mfma32(ones, pA0, lA);  lB = mfma32(ones, pB0, lB);                   \
    oA0 = mfma32(v10, pA1, oA0); oA1 = mfma32(v11, pA1, oA1);                  \
    oB0 = mfma32(v10, pB1, oB0); oB1 = mfma32(v11, pB1, oB1);                  \
    lA = mfma32(ones, pA1, lA);  lB = mfma32(ones, pB1, lB);                   \
    __builtin_amdgcn_s_setprio(0);                                             \
  }

  // clean vmcnt baseline (Q-frag loads drained), then prime 2 tiles
  asm volatile("s_waitcnt vmcnt(0)" ::: "memory");
  STAGE(0, 0);
  STAGE(1, 1);

#pragma unroll 1
  for (int t = 0; t < 31; ++t) {
    asm volatile("s_waitcnt vmcnt(8)" ::: "memory");  // tile t landed; t+1 in flight
    COMPUTE(t & 1);
    asm volatile("s_waitcnt lgkmcnt(0)" ::: "memory"); // reads of buf retired
    if (t < 30) STAGE(t + 2, t & 1);
  }
  asm volatile("s_waitcnt vmcnt(0)" ::: "memory");
  COMPUTE(1);

#undef STAGE
#undef COMPUTE

  // ---- combine s-halves (one barrier; unnormalized => plain adds) ----
  __syncthreads();
  float* reg = (float*)(LDS) + qh * 8192 + lane * 72;  // 288 B/lane record
  if (sh == 1) {
    float4* w4 = (float4*)reg;
#pragma unroll
    for (int i = 0; i < 4; ++i) {
      w4[i]      = make_float4(oA0[4*i], oA0[4*i+1], oA0[4*i+2], oA0[4*i+3]);
      w4[4 + i]  = make_float4(oA1[4*i], oA1[4*i+1], oA1[4*i+2], oA1[4*i+3]);
      w4[8 + i]  = make_float4(oB0[4*i], oB0[4*i+1], oB0[4*i+2], oB0[4*i+3]);
      w4[12 + i] = make_float4(oB1[4*i], oB1[4*i+1], oB1[4*i+2], oB1[4*i+3]);
    }
    reg[64] = lA[0]; reg[65] = lB[0];
  }
  __syncthreads();
  if (sh == 0) {
#pragma unroll
    for (int i = 0; i < 16; ++i) {
      oA0[i] += reg[i];      oA1[i] += reg[16 + i];
      oB0[i] += reg[32 + i]; oB1[i] += reg[48 + i];
    }
    float invA = 1.f / (lA[0] + reg[64]);
    float invB = 1.f / (lB[0] + reg[65]);
#pragma unroll
    for (int dblk = 0; dblk < 2; ++dblk) {
      const f32x16& a = dblk ? oA1 : oA0;
      const f32x16& bb = dblk ? oB1 : oB0;
#pragma unroll
      for (int rg = 0; rg < 4; ++rg) {
        int d0 = dblk * 32 + rg * 8 + hl * 4;
        uint2 w;
        w.x = cvtpk(a[rg * 4 + 0] * invA, a[rg * 4 + 1] * invA);
        w.y = cvtpk(a[rg * 4 + 2] * invA, a[rg * 4 + 3] * invA);
        *(uint2*)(Og + ((size_t)b * 2048 + q0) * 512 + h * 64 + d0) = w;
        w.x = cvtpk(bb[rg * 4 + 0] * invB, bb[rg * 4 + 1] * invB);
        w.y = cvtpk(bb[rg * 4 + 2] * invB, bb[rg * 4 + 3] * invB);
        *(uint2*)(Og + ((size_t)b * 2048 + q0 + 32) * 512 + h * 64 + d0) = w;
      }
    }
  }
}

// ---------------------------------------------------------------------------
extern "C" void kernel_launch(void* const* d_in, const int* in_sizes, int n_in,
                              void* d_out, int out_size, void* d_ws, size_t ws_size,
                              hipStream_t stream) {
  (void)in_sizes; (void)n_in; (void)out_size; (void)ws_size;
  const float* query = (const float*)d_in[0];
  const float* key   = (const float*)d_in[1];
  const float* value = (const float*)d_in[2];
  const float* Wq    = (const float*)d_in[3];
  const float* Wk    = (const float*)d_in[4];
  const float* Wv    = (const float*)d_in[5];
  const float* Wo    = (const float*)d_in[6];

  const size_t TOK = (size_t)NB * NL * MODEL;  // 4,194,304
  unsigned short* Qw  = (unsigned short*)d_ws;
  unsigned short* Kw  = Qw + TOK;
  unsigned short* Vw  = Kw + TOK;   // transposed [b][h*64+d][s]
  unsigned short* Aw  = Vw + TOK;   // attended [b][l][512]
  unsigned short* Wb  = Aw + TOK;   // Wqb|Wkb|Wvb|Wob, 4 x 262144 bf16

  cvtW<<<256, 256, 0, stream>>>(Wq, Wk, Wv, Wo, Wb);
  qkv512<<<768, 256, 0, stream>>>(query, key, value, Wb, Qw, Kw, Vw);
  attn_nb<<<512, 256, 0, stream>>>(Qw, Kw, Vw, Aw);
  gemmWo<<<256, 256, 0, stream>>>(Aw, Wb + 3 * 262144, (float*)d_out);
}

// Round 12
// 117.981 us; speedup vs baseline: 1.0549x; 1.0549x over previous
//
#include <hip/hip_runtime.h>
#include <stdint.h>
#include <stddef.h>

#define NB 4
#define NL 2048
#define MODEL 512
#define NH 8
#define HD 64

// Q pre-scale: (1/sqrt(64)) * log2(e) -> scores in log2 domain
#define QSCALE 0.18033688011112042f

typedef __attribute__((ext_vector_type(8))) short short8;
typedef __attribute__((ext_vector_type(8))) __bf16 bf16x8;
typedef __attribute__((ext_vector_type(4))) float f32x4;
typedef __attribute__((ext_vector_type(16))) float f32x16;
typedef __attribute__((ext_vector_type(2))) unsigned int u32x2;

// round-to-nearest-even fp32 -> bf16 (bit pattern)
static __device__ __forceinline__ unsigned short f2bf(float x) {
  union { float f; unsigned u; } v; v.f = x;
  unsigned r = v.u + 0x7FFFu + ((v.u >> 16) & 1u);
  return (unsigned short)(r >> 16);
}

// packed fp32x2 -> bf16x2 (single HW instruction)
static __device__ __forceinline__ unsigned cvtpk(float lo, float hi) {
  unsigned r;
  asm("v_cvt_pk_bf16_f32 %0, %1, %2" : "=v"(r) : "v"(lo), "v"(hi));
  return r;
}

static __device__ __forceinline__ f32x4 mfma16(short8 a, short8 b, f32x4 c) {
  return __builtin_amdgcn_mfma_f32_16x16x32_bf16(
      __builtin_bit_cast(bf16x8, a), __builtin_bit_cast(bf16x8, b), c, 0, 0, 0);
}

static __device__ __forceinline__ f32x16 mfma32(short8 a, short8 b, f32x16 c) {
  return __builtin_amdgcn_mfma_f32_32x32x16_bf16(
      __builtin_bit_cast(bf16x8, a), __builtin_bit_cast(bf16x8, b), c, 0, 0, 0);
}

#define GLOAD_LDS(gp, lp)                                                      \
  __builtin_amdgcn_global_load_lds(                                            \
      (const __attribute__((address_space(1))) void*)(gp),                     \
      (__attribute__((address_space(3))) void*)(lp), 16, 0, 0)

// ---------------------------------------------------------------------------
// Merged Q/K/V projection: grid 768 = 3 x 256, 256 thr (4 waves 2x2).
// C[m][n] = A[m][k] * W[n][k]; which 0: Q bf16 (scaled), 1: K bf16,
// 2: V transposed Vt[b][n][s].   (r7 version, verbatim)
// ---------------------------------------------------------------------------
__global__ __launch_bounds__(256) void qkv512(const float* __restrict__ Aq,
                                              const float* __restrict__ Ak,
                                              const float* __restrict__ Av,
                                              const float* __restrict__ Wqp,
                                              const float* __restrict__ Wkp,
                                              const float* __restrict__ Wvp,
                                              unsigned short* __restrict__ Qo,
                                              unsigned short* __restrict__ Ko,
                                              unsigned short* __restrict__ Vto) {
  __shared__ unsigned short Alds[128][72];
  __shared__ unsigned short Wlds[128][72];

  const int which = blockIdx.x >> 8;
  const int bid = blockIdx.x & 255;
  const float* A = which == 0 ? Aq : which == 1 ? Ak : Av;
  const float* W = which == 0 ? Wqp : which == 1 ? Wkp : Wvp;

  const int tid = threadIdx.x;
  const int bn = bid & 3;
  const int bm = bid >> 2;
  const int mbase = bm * 128, nbase = bn * 128;
  const int wid = tid >> 6, lane = tid & 63;
  const int lo = lane & 15, grp = lane >> 4;
  const int wm = wid >> 1, wn = wid & 1;

  f32x4 acc[4][4] = {};

#pragma unroll 1
  for (int kb = 0; kb < 8; ++kb) {
#pragma unroll
    for (int it = 0; it < 8; ++it) {
      int id = tid + it * 256;
      int row = id >> 4, cg = id & 15;
      float4 v = *(const float4*)(A + (size_t)(mbase + row) * 512 + kb * 64 + cg * 4);
      uint2 w; w.x = cvtpk(v.x, v.y); w.y = cvtpk(v.z, v.w);
      *(uint2*)&Alds[row][cg * 4] = w;
    }
#pragma unroll
    for (int it = 0; it < 8; ++it) {
      int id = tid + it * 256;
      int row = id >> 4, cg = id & 15;
      float4 v = *(const float4*)(W + (size_t)(nbase + row) * 512 + kb * 64 + cg * 4);
      uint2 w; w.x = cvtpk(v.x, v.y); w.y = cvtpk(v.z, v.w);
      *(uint2*)&Wlds[row][cg * 4] = w;
    }
    __syncthreads();

#pragma unroll
    for (int kk = 0; kk < 2; ++kk) {
      short8 aw[4], ba[4];
#pragma unroll
      for (int f = 0; f < 4; ++f)
        aw[f] = *(const short8*)&Wlds[wn * 64 + f * 16 + lo][kk * 32 + grp * 8];
#pragma unroll
      for (int f = 0; f < 4; ++f)
        ba[f] = *(const short8*)&Alds[wm * 64 + f * 16 + lo][kk * 32 + grp * 8];
#pragma unroll
      for (int mf = 0; mf < 4; ++mf)
#pragma unroll
        for (int nf = 0; nf < 4; ++nf)
          acc[mf][nf] = mfma16(aw[nf], ba[mf], acc[mf][nf]);
    }
    __syncthreads();
  }

  const float scale = (which == 0) ? QSCALE : 1.0f;
#pragma unroll
  for (int mf = 0; mf < 4; ++mf)
#pragma unroll
    for (int nf = 0; nf < 4; ++nf) {
      int m = mbase + wm * 64 + mf * 16 + lo;
      int n0 = nbase + wn * 64 + nf * 16 + grp * 4;
      f32x4 a = acc[mf][nf];
      if (which < 2) {
        unsigned short* C = which == 0 ? Qo : Ko;
        uint2 w;
        w.x = cvtpk(a[0] * scale, a[1] * scale);
        w.y = cvtpk(a[2] * scale, a[3] * scale);
        *(uint2*)(C + (size_t)m * 512 + n0) = w;
      } else {
        int b = m >> 11, s = m & 2047;
#pragma unroll
        for (int i = 0; i < 4; ++i)
          Vto[((size_t)b * 512 + n0 + i) * 2048 + s] = f2bf(a[i]);
      }
    }
}

// ---------------------------------------------------------------------------
// Output projection (bf16 A, fp32 out). 128x128 tiles, grid 256. (r7 verbatim)
// ---------------------------------------------------------------------------
__global__ __launch_bounds__(256) void gemmWo(const unsigned short* __restrict__ A,
                                              const float* __restrict__ W,
                                              float* __restrict__ C) {
  __shared__ unsigned short Alds[128][72];
  __shared__ unsigned short Wlds[128][72];

  const int tid = threadIdx.x;
  const int bn = blockIdx.x & 3;
  const int bm = blockIdx.x >> 2;
  const int mbase = bm * 128, nbase = bn * 128;
  const int wid = tid >> 6, lane = tid & 63;
  const int lo = lane & 15, grp = lane >> 4;
  const int wm = wid >> 1, wn = wid & 1;

  f32x4 acc[4][4] = {};

#pragma unroll 1
  for (int kb = 0; kb < 8; ++kb) {
#pragma unroll
    for (int it = 0; it < 4; ++it) {
      int id = tid + it * 256;
      int row = id >> 3, cg = id & 7;
      uint4 v = *(const uint4*)(A + (size_t)(mbase + row) * 512 + kb * 64 + cg * 8);
      *(uint4*)&Alds[row][cg * 8] = v;
    }
#pragma unroll
    for (int it = 0; it < 8; ++it) {
      int id = tid + it * 256;
      int row = id >> 4, cg = id & 15;
      float4 v = *(const float4*)(W + (size_t)(nbase + row) * 512 + kb * 64 + cg * 4);
      uint2 w; w.x = cvtpk(v.x, v.y); w.y = cvtpk(v.z, v.w);
      *(uint2*)&Wlds[row][cg * 4] = w;
    }
    __syncthreads();

#pragma unroll
    for (int kk = 0; kk < 2; ++kk) {
      short8 aw[4], ba[4];
#pragma unroll
      for (int f = 0; f < 4; ++f)
        aw[f] = *(const short8*)&Wlds[wn * 64 + f * 16 + lo][kk * 32 + grp * 8];
#pragma unroll
      for (int f = 0; f < 4; ++f)
        ba[f] = *(const short8*)&Alds[wm * 64 + f * 16 + lo][kk * 32 + grp * 8];
#pragma unroll
      for (int mf = 0; mf < 4; ++mf)
#pragma unroll
        for (int nf = 0; nf < 4; ++nf)
          acc[mf][nf] = mfma16(aw[nf], ba[mf], acc[mf][nf]);
    }
    __syncthreads();
  }

#pragma unroll
  for (int mf = 0; mf < 4; ++mf)
#pragma unroll
    for (int nf = 0; nf < 4; ++nf) {
      int m = mbase + wm * 64 + mf * 16 + lo;
      int n0 = nbase + wn * 64 + nf * 16 + grp * 4;
      f32x4 a = acc[mf][nf];
      float4 o;
      o.x = a[0]; o.y = a[1]; o.z = a[2]; o.w = a[3];
      *(float4*)(C + (size_t)m * 512 + n0) = o;
    }
}

// ---------------------------------------------------------------------------
// Flash attention = r7 attn64 (best measured: 66.5 us) + ONE delta:
// l computed via ones-MFMA (r9-proven) instead of VALU psum+shuffles.
// 4 waves = (q-half x s-half); each wave: 64 q (dual 32-q MFMA chains),
// 16 S-tiles of 64. K+V LDS via global_load_lds DMA (pre-swizzled source,
// XOR b128 reads), double-buffered per half. Unnormalized softmax.
// Grid 512 (2 blocks/CU). XCD chunk swizzle.
// ---------------------------------------------------------------------------
__global__ __launch_bounds__(256, 2) void attn64(const unsigned short* __restrict__ Qg,
                                                 const unsigned short* __restrict__ Kg,
                                                 const unsigned short* __restrict__ Vt,
                                                 unsigned short* __restrict__ Og) {
  __shared__ __align__(16) char LDS[65536];
  char* Kbase = LDS;            // [sh][buf][8192]
  char* Vbase = LDS + 32768;    // [sh][buf][8192]
  float* cb = (float*)LDS;      // combine buffer (aliases K/V, used after loop)

  const int tid = threadIdx.x;
  const int wid = tid >> 6, lane = tid & 63;
  const int ln31 = lane & 31, hl = lane >> 5;
  const int qh = wid & 1, sh = wid >> 1;

  // XCD chunk swizzle: each XCD gets 64 consecutive lb = 4 bh groups
  const int lb = ((blockIdx.x & 7) << 6) | (blockIdx.x >> 3);
  const int bh = lb >> 4, qb = lb & 15;
  const int b = bh >> 3, h = bh & 7;

  const unsigned short* Kbh = Kg + (size_t)b * 2048 * 512 + h * 64;
  const unsigned short* Vbh = Vt + ((size_t)b * 512 + h * 64) * 2048;

  const int q0 = qb * 128 + qh * 64 + ln31;   // chain A q; chain B = q0+32

  short8 qfA[4], qfB[4];
#pragma unroll
  for (int ks = 0; ks < 4; ++ks) {
    qfA[ks] = *(const short8*)(Qg + ((size_t)b * 2048 + q0) * 512 + h * 64 + ks * 16 + hl * 8);
    qfB[ks] = *(const short8*)(Qg + ((size_t)b * 2048 + q0 + 32) * 512 + h * 64 + ks * 16 + hl * 8);
  }

  // DMA staging: wave stages rows qh*32 .. qh*32+31 of its s-half's tile.
  // LDS linear; source pre-swizzled: LDS[row][slot] = G[row][slot ^ (row&7)]
  const int srow = lane >> 3;
  const int schunk = (lane & 7) ^ srow;
  const unsigned short* kgp = Kbh + (size_t)(sh * 16 * 64 + qh * 32 + srow) * 512 + schunk * 8;
  const unsigned short* vgp = Vbh + (size_t)(qh * 32 + srow) * 2048 + sh * 16 * 64 + schunk * 8;
  char* kd = Kbase + sh * 16384;
  char* vd = Vbase + sh * 16384;
  const int wofs = qh * 4096;

  // swizzled b128 read addressing
  const int rb0 = ln31 * 128, rb1 = rb0 + 4096;
  const int sw = (ln31 & 7) << 4;
  const int hl16 = hl * 16;

  const short8 ones = {0x3F80, 0x3F80, 0x3F80, 0x3F80, 0x3F80, 0x3F80, 0x3F80, 0x3F80};
  f32x16 oA0 = {}, oA1 = {}, oB0 = {}, oB1 = {}, lA = {}, lB = {};

  // prologue: stage this half's tile 0
#pragma unroll
  for (int g = 0; g < 4; ++g) {
    GLOAD_LDS(kgp + (size_t)g * 8 * 512, kd + wofs + g * 1024);
    GLOAD_LDS(vgp + (size_t)g * 8 * 2048, vd + wofs + g * 1024);
  }
  __syncthreads();

  int cur = 0;
#pragma unroll 1
  for (int t = 0; t < 16; ++t) {
    if (t < 15) {
      const unsigned short* kp = kgp + (size_t)(t + 1) * 64 * 512;
      const unsigned short* vp = vgp + (t + 1) * 64;
      char* kdn = kd + (cur ^ 1) * 8192 + wofs;
      char* vdn = vd + (cur ^ 1) * 8192 + wofs;
#pragma unroll
      for (int g = 0; g < 4; ++g) {
        GLOAD_LDS(kp + (size_t)g * 8 * 512, kdn + g * 1024);
        GLOAD_LDS(vp + (size_t)g * 8 * 2048, vdn + g * 1024);
      }
    }

    const char* kr = kd + cur * 8192;
    const char* vr = vd + cur * 8192;

    // ---- QK^T: both chains share K frags ----
    f32x16 sA0 = {}, sA1 = {}, sB0 = {}, sB1 = {};
    __builtin_amdgcn_s_setprio(1);
#pragma unroll
    for (int ks = 0; ks < 4; ++ks) {
      short8 k0 = *(const short8*)(kr + rb0 + ((ks * 32 + hl16) ^ sw));
      short8 k1 = *(const short8*)(kr + rb1 + ((ks * 32 + hl16) ^ sw));
      sA0 = mfma32(k0, qfA[ks], sA0);
      sA1 = mfma32(k1, qfA[ks], sA1);
      sB0 = mfma32(k0, qfB[ks], sB0);
      sB1 = mfma32(k1, qfB[ks], sB1);
    }
    __builtin_amdgcn_s_setprio(0);

    // ---- unnormalized softmax: P = exp2(s) directly (no psum -- l via MFMA)
    unsigned cA0[8], cA1[8], cB0[8], cB1[8];
#pragma unroll
    for (int i = 0; i < 8; ++i)
      cA0[i] = cvtpk(__builtin_exp2f(sA0[2 * i]), __builtin_exp2f(sA0[2 * i + 1]));
#pragma unroll
    for (int i = 0; i < 8; ++i)
      cA1[i] = cvtpk(__builtin_exp2f(sA1[2 * i]), __builtin_exp2f(sA1[2 * i + 1]));
#pragma unroll
    for (int i = 0; i < 8; ++i)
      cB0[i] = cvtpk(__builtin_exp2f(sB0[2 * i]), __builtin_exp2f(sB0[2 * i + 1]));
#pragma unroll
    for (int i = 0; i < 8; ++i)
      cB1[i] = cvtpk(__builtin_exp2f(sB1[2 * i]), __builtin_exp2f(sB1[2 * i + 1]));

    // ---- redistribute P into PV B-fragments (permlane32_swap) ----
    {
      u32x2 r;
      r = __builtin_amdgcn_permlane32_swap(cA0[0], cA0[2], false, false); cA0[0] = r[0]; cA0[2] = r[1];
      r = __builtin_amdgcn_permlane32_swap(cA0[1], cA0[3], false, false); cA0[1] = r[0]; cA0[3] = r[1];
      r = __builtin_amdgcn_permlane32_swap(cA0[4], cA0[6], false, false); cA0[4] = r[0]; cA0[6] = r[1];
      r = __builtin_amdgcn_permlane32_swap(cA0[5], cA0[7], false, false); cA0[5] = r[0]; cA0[7] = r[1];
      r = __builtin_amdgcn_permlane32_swap(cA1[0], cA1[2], false, false); cA1[0] = r[0]; cA1[2] = r[1];
      r = __builtin_amdgcn_permlane32_swap(cA1[1], cA1[3], false, false); cA1[1] = r[0]; cA1[3] = r[1];
      r = __builtin_amdgcn_permlane32_swap(cA1[4], cA1[6], false, false); cA1[4] = r[0]; cA1[6] = r[1];
      r = __builtin_amdgcn_permlane32_swap(cA1[5], cA1[7], false, false); cA1[5] = r[0]; cA1[7] = r[1];
      r = __builtin_amdgcn_permlane32_swap(cB0[0], cB0[2], false, false); cB0[0] = r[0]; cB0[2] = r[1];
      r = __builtin_amdgcn_permlane32_swap(cB0[1], cB0[3], false, false); cB0[1] = r[0]; cB0[3] = r[1];
      r = __builtin_amdgcn_permlane32_swap(cB0[4], cB0[6], false, false); cB0[4] = r[0]; cB0[6] = r[1];
      r = __builtin_amdgcn_permlane32_swap(cB0[5], cB0[7], false, false); cB0[5] = r[0]; cB0[7] = r[1];
      r = __builtin_amdgcn_permlane32_swap(cB1[0], cB1[2], false, false); cB1[0] = r[0]; cB1[2] = r[1];
      r = __builtin_amdgcn_permlane32_swap(cB1[1], cB1[3], false, false); cB1[1] = r[0]; cB1[3] = r[1];
      r = __builtin_amdgcn_permlane32_swap(cB1[4], cB1[6], false, false); cB1[4] = r[0]; cB1[6] = r[1];
      r = __builtin_amdgcn_permlane32_swap(cB1[5], cB1[7], false, false); cB1[5] = r[0]; cB1[7] = r[1];
    }
    short8 pfA[4], pfB[4];
    {
      union { unsigned u[4]; short8 s; } t2;
      t2.u[0] = cA0[0]; t2.u[1] = cA0[1]; t2.u[2] = cA0[2]; t2.u[3] = cA0[3]; pfA[0] = t2.s;
      t2.u[0] = cA0[4]; t2.u[1] = cA0[5]; t2.u[2] = cA0[6]; t2.u[3] = cA0[7]; pfA[1] = t2.s;
      t2.u[0] = cA1[0]; t2.u[1] = cA1[1]; t2.u[2] = cA1[2]; t2.u[3] = cA1[3]; pfA[2] = t2.s;
      t2.u[0] = cA1[4]; t2.u[1] = cA1[5]; t2.u[2] = cA1[6]; t2.u[3] = cA1[7]; pfA[3] = t2.s;
      t2.u[0] = cB0[0]; t2.u[1] = cB0[1]; t2.u[2] = cB0[2]; t2.u[3] = cB0[3]; pfB[0] = t2.s;
      t2.u[0] = cB0[4]; t2.u[1] = cB0[5]; t2.u[2] = cB0[6]; t2.u[3] = cB0[7]; pfB[1] = t2.s;
      t2.u[0] = cB1[0]; t2.u[1] = cB1[1]; t2.u[2] = cB1[2]; t2.u[3] = cB1[3]; pfB[2] = t2.s;
      t2.u[0] = cB1[4]; t2.u[1] = cB1[5]; t2.u[2] = cB1[6]; t2.u[3] = cB1[7]; pfB[3] = t2.s;
    }

    // ---- PV: both chains share V frags; l row-sum via ones-MFMA ----
    __builtin_amdgcn_s_setprio(1);
#pragma unroll
    for (int ks = 0; ks < 4; ++ks) {
      short8 v0 = *(const short8*)(vr + rb0 + ((ks * 32 + hl16) ^ sw));
      short8 v1 = *(const short8*)(vr + rb1 + ((ks * 32 + hl16) ^ sw));
      oA0 = mfma32(v0, pfA[ks], oA0);
      oA1 = mfma32(v1, pfA[ks], oA1);
      oB0 = mfma32(v0, pfB[ks], oB0);
      oB1 = mfma32(v1, pfB[ks], oB1);
      lA = mfma32(ones, pfA[ks], lA);
      lB = mfma32(ones, pfB[ks], lB);
    }
    __builtin_amdgcn_s_setprio(0);

    __syncthreads();
    cur ^= 1;
  }

  // ---- combine s-halves (trivial: o and l just add) ----
  float* myc = cb + (size_t)(qh * 64 + lane) * 68;
  if (sh == 1) {
    float4* c4 = (float4*)myc;
#pragma unroll
    for (int i = 0; i < 4; ++i) {
      c4[i]      = make_float4(oA0[4*i], oA0[4*i+1], oA0[4*i+2], oA0[4*i+3]);
      c4[4 + i]  = make_float4(oA1[4*i], oA1[4*i+1], oA1[4*i+2], oA1[4*i+3]);
      c4[8 + i]  = make_float4(oB0[4*i], oB0[4*i+1], oB0[4*i+2], oB0[4*i+3]);
      c4[12 + i] = make_float4(oB1[4*i], oB1[4*i+1], oB1[4*i+2], oB1[4*i+3]);
    }
    myc[64] = lA[0]; myc[65] = lB[0];
  }
  __syncthreads();
  if (sh == 0) {
#pragma unroll
    for (int i = 0; i < 16; ++i) {
      oA0[i] += myc[i];      oA1[i] += myc[16 + i];
      oB0[i] += myc[32 + i]; oB1[i] += myc[48 + i];
    }
    float invA = 1.f / (lA[0] + myc[64]);
    float invB = 1.f / (lB[0] + myc[65]);

#pragma unroll
    for (int dblk = 0; dblk < 2; ++dblk) {
      const f32x16& a = dblk ? oA1 : oA0;
      const f32x16& bb = dblk ? oB1 : oB0;
#pragma unroll
      for (int rg = 0; rg < 4; ++rg) {
        int d0 = dblk * 32 + rg * 8 + hl * 4;
        uint2 w;
        w.x = cvtpk(a[rg * 4 + 0] * invA, a[rg * 4 + 1] * invA);
        w.y = cvtpk(a[rg * 4 + 2] * invA, a[rg * 4 + 3] * invA);
        *(uint2*)(Og + ((size_t)b * 2048 + q0) * 512 + h * 64 + d0) = w;
        w.x = cvtpk(bb[rg * 4 + 0] * invB, bb[rg * 4 + 1] * invB);
        w.y = cvtpk(bb[rg * 4 + 2] * invB, bb[rg * 4 + 3] * invB);
        *(uint2*)(Og + ((size_t)b * 2048 + q0 + 32) * 512 + h * 64 + d0) = w;
      }
    }
  }
}

// ---------------------------------------------------------------------------
extern "C" void kernel_launch(void* const* d_in, const int* in_sizes, int n_in,
                              void* d_out, int out_size, void* d_ws, size_t ws_size,
                              hipStream_t stream) {
  (void)in_sizes; (void)n_in; (void)out_size; (void)ws_size;
  const float* query = (const float*)d_in[0];
  const float* key   = (const float*)d_in[1];
  const float* value = (const float*)d_in[2];
  const float* Wq    = (const float*)d_in[3];
  const float* Wk    = (const float*)d_in[4];
  const float* Wv    = (const float*)d_in[5];
  const float* Wo    = (const float*)d_in[6];

  const size_t TOK = (size_t)NB * NL * MODEL;
  unsigned short* Qw = (unsigned short*)d_ws;
  unsigned short* Kw = Qw + TOK;
  unsigned short* Vw = Kw + TOK;   // transposed [b][h*64+d][s]
  unsigned short* Aw = Vw + TOK;   // attended [b][l][512]

  qkv512<<<768, 256, 0, stream>>>(query, key, value, Wq, Wk, Wv, Qw, Kw, Vw);
  attn64<<<512, 256, 0, stream>>>(Qw, Kw, Vw, Aw);
  gemmWo<<<256, 256, 0, stream>>>(Aw, Wo, (float*)d_out);
}

// Round 13
// 115.083 us; speedup vs baseline: 1.0814x; 1.0252x over previous
//
#include <hip/hip_runtime.h>
#include <stdint.h>
#include <stddef.h>

#define NB 4
#define NL 2048
#define MODEL 512
#define NH 8
#define HD 64

// Q pre-scale: (1/sqrt(64)) * log2(e) -> scores in log2 domain
#define QSCALE 0.18033688011112042f

typedef __attribute__((ext_vector_type(8))) short short8;
typedef __attribute__((ext_vector_type(8))) __bf16 bf16x8;
typedef __attribute__((ext_vector_type(4))) float f32x4;
typedef __attribute__((ext_vector_type(16))) float f32x16;
typedef __attribute__((ext_vector_type(2))) unsigned int u32x2;

// round-to-nearest-even fp32 -> bf16 (bit pattern)
static __device__ __forceinline__ unsigned short f2bf(float x) {
  union { float f; unsigned u; } v; v.f = x;
  unsigned r = v.u + 0x7FFFu + ((v.u >> 16) & 1u);
  return (unsigned short)(r >> 16);
}

// packed fp32x2 -> bf16x2 (single HW instruction)
static __device__ __forceinline__ unsigned cvtpk(float lo, float hi) {
  unsigned r;
  asm("v_cvt_pk_bf16_f32 %0, %1, %2" : "=v"(r) : "v"(lo), "v"(hi));
  return r;
}

static __device__ __forceinline__ f32x4 mfma16(short8 a, short8 b, f32x4 c) {
  return __builtin_amdgcn_mfma_f32_16x16x32_bf16(
      __builtin_bit_cast(bf16x8, a), __builtin_bit_cast(bf16x8, b), c, 0, 0, 0);
}

static __device__ __forceinline__ f32x16 mfma32(short8 a, short8 b, f32x16 c) {
  return __builtin_amdgcn_mfma_f32_32x32x16_bf16(
      __builtin_bit_cast(bf16x8, a), __builtin_bit_cast(bf16x8, b), c, 0, 0, 0);
}

#define GLOAD_LDS(gp, lp)                                                      \
  __builtin_amdgcn_global_load_lds(                                            \
      (const __attribute__((address_space(1))) void*)(gp),                     \
      (__attribute__((address_space(3))) void*)(lp), 16, 0, 0)

// ---------------------------------------------------------------------------
// Merged Q/K/V projection: grid 768 = 3 x 256, 256 thr (4 waves 2x2).
// (r7 version, verbatim — measured-good)
// ---------------------------------------------------------------------------
__global__ __launch_bounds__(256) void qkv512(const float* __restrict__ Aq,
                                              const float* __restrict__ Ak,
                                              const float* __restrict__ Av,
                                              const float* __restrict__ Wqp,
                                              const float* __restrict__ Wkp,
                                              const float* __restrict__ Wvp,
                                              unsigned short* __restrict__ Qo,
                                              unsigned short* __restrict__ Ko,
                                              unsigned short* __restrict__ Vto) {
  __shared__ unsigned short Alds[128][72];
  __shared__ unsigned short Wlds[128][72];

  const int which = blockIdx.x >> 8;
  const int bid = blockIdx.x & 255;
  const float* A = which == 0 ? Aq : which == 1 ? Ak : Av;
  const float* W = which == 0 ? Wqp : which == 1 ? Wkp : Wvp;

  const int tid = threadIdx.x;
  const int bn = bid & 3;
  const int bm = bid >> 2;
  const int mbase = bm * 128, nbase = bn * 128;
  const int wid = tid >> 6, lane = tid & 63;
  const int lo = lane & 15, grp = lane >> 4;
  const int wm = wid >> 1, wn = wid & 1;

  f32x4 acc[4][4] = {};

#pragma unroll 1
  for (int kb = 0; kb < 8; ++kb) {
#pragma unroll
    for (int it = 0; it < 8; ++it) {
      int id = tid + it * 256;
      int row = id >> 4, cg = id & 15;
      float4 v = *(const float4*)(A + (size_t)(mbase + row) * 512 + kb * 64 + cg * 4);
      uint2 w; w.x = cvtpk(v.x, v.y); w.y = cvtpk(v.z, v.w);
      *(uint2*)&Alds[row][cg * 4] = w;
    }
#pragma unroll
    for (int it = 0; it < 8; ++it) {
      int id = tid + it * 256;
      int row = id >> 4, cg = id & 15;
      float4 v = *(const float4*)(W + (size_t)(nbase + row) * 512 + kb * 64 + cg * 4);
      uint2 w; w.x = cvtpk(v.x, v.y); w.y = cvtpk(v.z, v.w);
      *(uint2*)&Wlds[row][cg * 4] = w;
    }
    __syncthreads();

#pragma unroll
    for (int kk = 0; kk < 2; ++kk) {
      short8 aw[4], ba[4];
#pragma unroll
      for (int f = 0; f < 4; ++f)
        aw[f] = *(const short8*)&Wlds[wn * 64 + f * 16 + lo][kk * 32 + grp * 8];
#pragma unroll
      for (int f = 0; f < 4; ++f)
        ba[f] = *(const short8*)&Alds[wm * 64 + f * 16 + lo][kk * 32 + grp * 8];
#pragma unroll
      for (int mf = 0; mf < 4; ++mf)
#pragma unroll
        for (int nf = 0; nf < 4; ++nf)
          acc[mf][nf] = mfma16(aw[nf], ba[mf], acc[mf][nf]);
    }
    __syncthreads();
  }

  const float scale = (which == 0) ? QSCALE : 1.0f;
#pragma unroll
  for (int mf = 0; mf < 4; ++mf)
#pragma unroll
    for (int nf = 0; nf < 4; ++nf) {
      int m = mbase + wm * 64 + mf * 16 + lo;
      int n0 = nbase + wn * 64 + nf * 16 + grp * 4;
      f32x4 a = acc[mf][nf];
      if (which < 2) {
        unsigned short* C = which == 0 ? Qo : Ko;
        uint2 w;
        w.x = cvtpk(a[0] * scale, a[1] * scale);
        w.y = cvtpk(a[2] * scale, a[3] * scale);
        *(uint2*)(C + (size_t)m * 512 + n0) = w;
      } else {
        int b = m >> 11, s = m & 2047;
#pragma unroll
        for (int i = 0; i < 4; ++i)
          Vto[((size_t)b * 512 + n0 + i) * 2048 + s] = f2bf(a[i]);
      }
    }
}

// ---------------------------------------------------------------------------
// Output projection (bf16 A, fp32 out). 128x128 block tile, grid 256, but
// 512 threads = 8 waves (64m x 32n wave tiles) -> 2 waves/SIMD (was 1).
// ---------------------------------------------------------------------------
__global__ __launch_bounds__(512) void gemmWo(const unsigned short* __restrict__ A,
                                              const float* __restrict__ W,
                                              float* __restrict__ C) {
  __shared__ unsigned short Alds[128][72];
  __shared__ unsigned short Wlds[128][72];

  const int tid = threadIdx.x;
  const int bn = blockIdx.x & 3;
  const int bm = blockIdx.x >> 2;
  const int mbase = bm * 128, nbase = bn * 128;
  const int wid = tid >> 6, lane = tid & 63;
  const int lo = lane & 15, grp = lane >> 4;
  const int wm = wid >> 2, wn = wid & 3;     // 2 x 4 waves, 64m x 32n each

  f32x4 acc[4][2] = {};

#pragma unroll 1
  for (int kb = 0; kb < 8; ++kb) {
#pragma unroll
    for (int it = 0; it < 2; ++it) {
      int id = tid + it * 512;
      int row = id >> 3, cg = id & 7;
      uint4 v = *(const uint4*)(A + (size_t)(mbase + row) * 512 + kb * 64 + cg * 8);
      *(uint4*)&Alds[row][cg * 8] = v;
    }
#pragma unroll
    for (int it = 0; it < 4; ++it) {
      int id = tid + it * 512;
      int row = id >> 4, cg = id & 15;
      float4 v = *(const float4*)(W + (size_t)(nbase + row) * 512 + kb * 64 + cg * 4);
      uint2 w; w.x = cvtpk(v.x, v.y); w.y = cvtpk(v.z, v.w);
      *(uint2*)&Wlds[row][cg * 4] = w;
    }
    __syncthreads();

#pragma unroll
    for (int kk = 0; kk < 2; ++kk) {
      short8 aw[2], ba[4];
#pragma unroll
      for (int f = 0; f < 2; ++f)
        aw[f] = *(const short8*)&Wlds[wn * 32 + f * 16 + lo][kk * 32 + grp * 8];
#pragma unroll
      for (int f = 0; f < 4; ++f)
        ba[f] = *(const short8*)&Alds[wm * 64 + f * 16 + lo][kk * 32 + grp * 8];
#pragma unroll
      for (int mf = 0; mf < 4; ++mf)
#pragma unroll
        for (int nf = 0; nf < 2; ++nf)
          acc[mf][nf] = mfma16(aw[nf], ba[mf], acc[mf][nf]);
    }
    __syncthreads();
  }

#pragma unroll
  for (int mf = 0; mf < 4; ++mf)
#pragma unroll
    for (int nf = 0; nf < 2; ++nf) {
      int m = mbase + wm * 64 + mf * 16 + lo;
      int n0 = nbase + wn * 32 + nf * 16 + grp * 4;
      f32x4 a = acc[mf][nf];
      float4 o;
      o.x = a[0]; o.y = a[1]; o.z = a[2]; o.w = a[3];
      *(float4*)(C + (size_t)m * 512 + n0) = o;
    }
}

// ---------------------------------------------------------------------------
// Flash attention r13 = r12 structure with the tile body SOFTWARE-PIPELINED
// at half-tile granularity and setprio fences REMOVED:
//   QK-half1 -> QK-half2 (matrix) || softmax-half1 (VALU)
//   -> PV-half1 (matrix) || softmax-half2 (VALU) -> PV-half2
// Breaks the QK/softmax/PV phase-locking so MFMA and VALU pipes overlap.
// All math identical (pure reorder of independent ops).
// ---------------------------------------------------------------------------
__global__ __launch_bounds__(256, 2) void attn64(const unsigned short* __restrict__ Qg,
                                                 const unsigned short* __restrict__ Kg,
                                                 const unsigned short* __restrict__ Vt,
                                                 unsigned short* __restrict__ Og) {
  __shared__ __align__(16) char LDS[65536];
  char* Kbase = LDS;            // [sh][buf][8192]
  char* Vbase = LDS + 32768;    // [sh][buf][8192]
  float* cb = (float*)LDS;      // combine buffer (aliases K/V, used after loop)

  const int tid = threadIdx.x;
  const int wid = tid >> 6, lane = tid & 63;
  const int ln31 = lane & 31, hl = lane >> 5;
  const int qh = wid & 1, sh = wid >> 1;

  // XCD chunk swizzle: each XCD gets 64 consecutive lb = 4 bh groups
  const int lb = ((blockIdx.x & 7) << 6) | (blockIdx.x >> 3);
  const int bh = lb >> 4, qb = lb & 15;
  const int b = bh >> 3, h = bh & 7;

  const unsigned short* Kbh = Kg + (size_t)b * 2048 * 512 + h * 64;
  const unsigned short* Vbh = Vt + ((size_t)b * 512 + h * 64) * 2048;

  const int q0 = qb * 128 + qh * 64 + ln31;   // chain A q; chain B = q0+32

  short8 qfA[4], qfB[4];
#pragma unroll
  for (int ks = 0; ks < 4; ++ks) {
    qfA[ks] = *(const short8*)(Qg + ((size_t)b * 2048 + q0) * 512 + h * 64 + ks * 16 + hl * 8);
    qfB[ks] = *(const short8*)(Qg + ((size_t)b * 2048 + q0 + 32) * 512 + h * 64 + ks * 16 + hl * 8);
  }

  // DMA staging: wave stages rows qh*32 .. qh*32+31 of its s-half's tile.
  // LDS linear; source pre-swizzled: LDS[row][slot] = G[row][slot ^ (row&7)]
  const int srow = lane >> 3;
  const int schunk = (lane & 7) ^ srow;
  const unsigned short* kgp = Kbh + (size_t)(sh * 16 * 64 + qh * 32 + srow) * 512 + schunk * 8;
  const unsigned short* vgp = Vbh + (size_t)(qh * 32 + srow) * 2048 + sh * 16 * 64 + schunk * 8;
  char* kd = Kbase + sh * 16384;
  char* vd = Vbase + sh * 16384;
  const int wofs = qh * 4096;

  // swizzled b128 read addressing
  const int rb0 = ln31 * 128, rb1 = rb0 + 4096;
  const int sw = (ln31 & 7) << 4;
  const int hl16 = hl * 16;

  const short8 ones = {0x3F80, 0x3F80, 0x3F80, 0x3F80, 0x3F80, 0x3F80, 0x3F80, 0x3F80};
  f32x16 oA0 = {}, oA1 = {}, oB0 = {}, oB1 = {}, lA = {}, lB = {};

  // prologue: stage this half's tile 0
#pragma unroll
  for (int g = 0; g < 4; ++g) {
    GLOAD_LDS(kgp + (size_t)g * 8 * 512, kd + wofs + g * 1024);
    GLOAD_LDS(vgp + (size_t)g * 8 * 2048, vd + wofs + g * 1024);
  }
  __syncthreads();

  int cur = 0;
#pragma unroll 1
  for (int t = 0; t < 16; ++t) {
    if (t < 15) {
      const unsigned short* kp = kgp + (size_t)(t + 1) * 64 * 512;
      const unsigned short* vp = vgp + (t + 1) * 64;
      char* kdn = kd + (cur ^ 1) * 8192 + wofs;
      char* vdn = vd + (cur ^ 1) * 8192 + wofs;
#pragma unroll
      for (int g = 0; g < 4; ++g) {
        GLOAD_LDS(kp + (size_t)g * 8 * 512, kdn + g * 1024);
        GLOAD_LDS(vp + (size_t)g * 8 * 2048, vdn + g * 1024);
      }
    }

    const char* kr = kd + cur * 8192;
    const char* vr = vd + cur * 8192;

    // ================= QK half1: s-rows 0..31 =================
    f32x16 sA0 = {}, sB0 = {};
#pragma unroll
    for (int ks = 0; ks < 4; ++ks) {
      short8 k0 = *(const short8*)(kr + rb0 + ((ks * 32 + hl16) ^ sw));
      sA0 = mfma32(k0, qfA[ks], sA0);
      sB0 = mfma32(k0, qfB[ks], sB0);
    }
    // ================= QK half2: s-rows 32..63 =================
    f32x16 sA1 = {}, sB1 = {};
#pragma unroll
    for (int ks = 0; ks < 4; ++ks) {
      short8 k1 = *(const short8*)(kr + rb1 + ((ks * 32 + hl16) ^ sw));
      sA1 = mfma32(k1, qfA[ks], sA1);
      sB1 = mfma32(k1, qfB[ks], sB1);
    }

    // ===== softmax half1 (VALU; overlaps QK half2's MFMA issue) =====
    unsigned cA0[8], cB0[8];
#pragma unroll
    for (int i = 0; i < 8; ++i)
      cA0[i] = cvtpk(__builtin_exp2f(sA0[2 * i]), __builtin_exp2f(sA0[2 * i + 1]));
#pragma unroll
    for (int i = 0; i < 8; ++i)
      cB0[i] = cvtpk(__builtin_exp2f(sB0[2 * i]), __builtin_exp2f(sB0[2 * i + 1]));
    {
      u32x2 r;
      r = __builtin_amdgcn_permlane32_swap(cA0[0], cA0[2], false, false); cA0[0] = r[0]; cA0[2] = r[1];
      r = __builtin_amdgcn_permlane32_swap(cA0[1], cA0[3], false, false); cA0[1] = r[0]; cA0[3] = r[1];
      r = __builtin_amdgcn_permlane32_swap(cA0[4], cA0[6], false, false); cA0[4] = r[0]; cA0[6] = r[1];
      r = __builtin_amdgcn_permlane32_swap(cA0[5], cA0[7], false, false); cA0[5] = r[0]; cA0[7] = r[1];
      r = __builtin_amdgcn_permlane32_swap(cB0[0], cB0[2], false, false); cB0[0] = r[0]; cB0[2] = r[1];
      r = __builtin_amdgcn_permlane32_swap(cB0[1], cB0[3], false, false); cB0[1] = r[0]; cB0[3] = r[1];
      r = __builtin_amdgcn_permlane32_swap(cB0[4], cB0[6], false, false); cB0[4] = r[0]; cB0[6] = r[1];
      r = __builtin_amdgcn_permlane32_swap(cB0[5], cB0[7], false, false); cB0[5] = r[0]; cB0[7] = r[1];
    }
    short8 pfA0, pfA1, pfB0, pfB1;
    {
      union { unsigned u[4]; short8 s; } t2;
      t2.u[0] = cA0[0]; t2.u[1] = cA0[1]; t2.u[2] = cA0[2]; t2.u[3] = cA0[3]; pfA0 = t2.s;
      t2.u[0] = cA0[4]; t2.u[1] = cA0[5]; t2.u[2] = cA0[6]; t2.u[3] = cA0[7]; pfA1 = t2.s;
      t2.u[0] = cB0[0]; t2.u[1] = cB0[1]; t2.u[2] = cB0[2]; t2.u[3] = cB0[3]; pfB0 = t2.s;
      t2.u[0] = cB0[4]; t2.u[1] = cB0[5]; t2.u[2] = cB0[6]; t2.u[3] = cB0[7]; pfB1 = t2.s;
    }

    // ================= PV half1 (ks 0,1) =================
#pragma unroll
    for (int ks = 0; ks < 2; ++ks) {
      short8 pf = ks ? pfA1 : pfA0;
      short8 pg = ks ? pfB1 : pfB0;
      short8 v0 = *(const short8*)(vr + rb0 + ((ks * 32 + hl16) ^ sw));
      short8 v1 = *(const short8*)(vr + rb1 + ((ks * 32 + hl16) ^ sw));
      oA0 = mfma32(v0, pf, oA0);
      oA1 = mfma32(v1, pf, oA1);
      oB0 = mfma32(v0, pg, oB0);
      oB1 = mfma32(v1, pg, oB1);
      lA = mfma32(ones, pf, lA);
      lB = mfma32(ones, pg, lB);
    }

    // ===== softmax half2 (VALU; overlaps PV half1's MFMA issue) =====
    unsigned cA1[8], cB1[8];
#pragma unroll
    for (int i = 0; i < 8; ++i)
      cA1[i] = cvtpk(__builtin_exp2f(sA1[2 * i]), __builtin_exp2f(sA1[2 * i + 1]));
#pragma unroll
    for (int i = 0; i < 8; ++i)
      cB1[i] = cvtpk(__builtin_exp2f(sB1[2 * i]), __builtin_exp2f(sB1[2 * i + 1]));
    {
      u32x2 r;
      r = __builtin_amdgcn_permlane32_swap(cA1[0], cA1[2], false, false); cA1[0] = r[0]; cA1[2] = r[1];
      r = __builtin_amdgcn_permlane32_swap(cA1[1], cA1[3], false, false); cA1[1] = r[0]; cA1[3] = r[1];
      r = __builtin_amdgcn_permlane32_swap(cA1[4], cA1[6], false, false); cA1[4] = r[0]; cA1[6] = r[1];
      r = __builtin_amdgcn_permlane32_swap(cA1[5], cA1[7], false, false); cA1[5] = r[0]; cA1[7] = r[1];
      r = __builtin_amdgcn_permlane32_swap(cB1[0], cB1[2], false, false); cB1[0] = r[0]; cB1[2] = r[1];
      r = __builtin_amdgcn_permlane32_swap(cB1[1], cB1[3], false, false); cB1[1] = r[0]; cB1[3] = r[1];
      r = __builtin_amdgcn_permlane32_swap(cB1[4], cB1[6], false, false); cB1[4] = r[0]; cB1[6] = r[1];
      r = __builtin_amdgcn_permlane32_swap(cB1[5], cB1[7], false, false); cB1[5] = r[0]; cB1[7] = r[1];
    }
    short8 pfA2, pfA3, pfB2, pfB3;
    {
      union { unsigned u[4]; short8 s; } t2;
      t2.u[0] = cA1[0]; t2.u[1] = cA1[1]; t2.u[2] = cA1[2]; t2.u[3] = cA1[3]; pfA2 = t2.s;
      t2.u[0] = cA1[4]; t2.u[1] = cA1[5]; t2.u[2] = cA1[6]; t2.u[3] = cA1[7]; pfA3 = t2.s;
      t2.u[0] = cB1[0]; t2.u[1] = cB1[1]; t2.u[2] = cB1[2]; t2.u[3] = cB1[3]; pfB2 = t2.s;
      t2.u[0] = cB1[4]; t2.u[1] = cB1[5]; t2.u[2] = cB1[6]; t2.u[3] = cB1[7]; pfB3 = t2.s;
    }

    // ================= PV half2 (ks 2,3) =================
#pragma unroll
    for (int ks = 2; ks < 4; ++ks) {
      short8 pf = (ks == 2) ? pfA2 : pfA3;
      short8 pg = (ks == 2) ? pfB2 : pfB3;
      short8 v0 = *(const short8*)(vr + rb0 + ((ks * 32 + hl16) ^ sw));
      short8 v1 = *(const short8*)(vr + rb1 + ((ks * 32 + hl16) ^ sw));
      oA0 = mfma32(v0, pf, oA0);
      oA1 = mfma32(v1, pf, oA1);
      oB0 = mfma32(v0, pg, oB0);
      oB1 = mfma32(v1, pg, oB1);
      lA = mfma32(ones, pf, lA);
      lB = mfma32(ones, pg, lB);
    }

    __syncthreads();
    cur ^= 1;
  }

  // ---- combine s-halves (trivial: o and l just add) ----
  float* myc = cb + (size_t)(qh * 64 + lane) * 68;
  if (sh == 1) {
    float4* c4 = (float4*)myc;
#pragma unroll
    for (int i = 0; i < 4; ++i) {
      c4[i]      = make_float4(oA0[4*i], oA0[4*i+1], oA0[4*i+2], oA0[4*i+3]);
      c4[4 + i]  = make_float4(oA1[4*i], oA1[4*i+1], oA1[4*i+2], oA1[4*i+3]);
      c4[8 + i]  = make_float4(oB0[4*i], oB0[4*i+1], oB0[4*i+2], oB0[4*i+3]);
      c4[12 + i] = make_float4(oB1[4*i], oB1[4*i+1], oB1[4*i+2], oB1[4*i+3]);
    }
    myc[64] = lA[0]; myc[65] = lB[0];
  }
  __syncthreads();
  if (sh == 0) {
#pragma unroll
    for (int i = 0; i < 16; ++i) {
      oA0[i] += myc[i];      oA1[i] += myc[16 + i];
      oB0[i] += myc[32 + i]; oB1[i] += myc[48 + i];
    }
    float invA = 1.f / (lA[0] + myc[64]);
    float invB = 1.f / (lB[0] + myc[65]);

#pragma unroll
    for (int dblk = 0; dblk < 2; ++dblk) {
      const f32x16& a = dblk ? oA1 : oA0;
      const f32x16& bb = dblk ? oB1 : oB0;
#pragma unroll
      for (int rg = 0; rg < 4; ++rg) {
        int d0 = dblk * 32 + rg * 8 + hl * 4;
        uint2 w;
        w.x = cvtpk(a[rg * 4 + 0] * invA, a[rg * 4 + 1] * invA);
        w.y = cvtpk(a[rg * 4 + 2] * invA, a[rg * 4 + 3] * invA);
        *(uint2*)(Og + ((size_t)b * 2048 + q0) * 512 + h * 64 + d0) = w;
        w.x = cvtpk(bb[rg * 4 + 0] * invB, bb[rg * 4 + 1] * invB);
        w.y = cvtpk(bb[rg * 4 + 2] * invB, bb[rg * 4 + 3] * invB);
        *(uint2*)(Og + ((size_t)b * 2048 + q0 + 32) * 512 + h * 64 + d0) = w;
      }
    }
  }
}

// ---------------------------------------------------------------------------
extern "C" void kernel_launch(void* const* d_in, const int* in_sizes, int n_in,
                              void* d_out, int out_size, void* d_ws, size_t ws_size,
                              hipStream_t stream) {
  (void)in_sizes; (void)n_in; (void)out_size; (void)ws_size;
  const float* query = (const float*)d_in[0];
  const float* key   = (const float*)d_in[1];
  const float* value = (const float*)d_in[2];
  const float* Wq    = (const float*)d_in[3];
  const float* Wk    = (const float*)d_in[4];
  const float* Wv    = (const float*)d_in[5];
  const float* Wo    = (const float*)d_in[6];

  const size_t TOK = (size_t)NB * NL * MODEL;
  unsigned short* Qw = (unsigned short*)d_ws;
  unsigned short* Kw = Qw + TOK;
  unsigned short* Vw = Kw + TOK;   // transposed [b][h*64+d][s]
  unsigned short* Aw = Vw + TOK;   // attended [b][l][512]

  qkv512<<<768, 256, 0, stream>>>(query, key, value, Wq, Wk, Wv, Qw, Kw, Vw);
  attn64<<<512, 256, 0, stream>>>(Qw, Kw, Vw, Aw);
  gemmWo<<<256, 512, 0, stream>>>(Aw, Wo, (float*)d_out);
}